// Round 11
// baseline (487.584 us; speedup 1.0000x reference)
//
#include <hip/hip_runtime.h>
#include <cstdint>

#define SLOPE 0.33f

static constexpr int B_   = 64;
static constexpr int E1_  = 8978;
static constexpr int E2_  = 4489;
static constexpr int N1_  = B_ * E1_;      // 574592
static constexpr int N2_  = B_ * E2_;      // 287296
static constexpr int DEG_ = 16;
static constexpr int SLC1_ = 562;          // ceil(E1_/16)
static constexpr int SLC2_ = 281;          // ceil(E2_/16)
static constexpr double EPS_ = 1e-5;

typedef unsigned short u16;
typedef unsigned int   u32;

__device__ __forceinline__ float lrelu(float v) { return v > 0.f ? v : SLOPE * v; }
__device__ __forceinline__ float dot4(float4 a, float4 b) {
  return a.x * b.x + a.y * b.y + a.z * b.z + a.w * b.w;
}
__device__ __forceinline__ void gacc(float4& acc, float wgt, const float4& gv) {
  acc.x += wgt * gv.x; acc.y += wgt * gv.y; acc.z += wgt * gv.z; acc.w += wgt * gv.w;
}

// ---------------------------------------------------------------------
// merged prep: lsrc1 (2245 blocks) | lsrc2 (1123 blocks) | qb (16 blocks)
// ---------------------------------------------------------------------
template<int NPG>
__device__ __forceinline__ void comp_idx(const int* __restrict__ src, int node,
    u16* __restrict__ out) {
  int gbase = (node / NPG) * NPG;
  const int4* s4 = (const int4*)(src + (size_t)node * DEG_);
  int4 a = s4[0], b = s4[1], c = s4[2], d = s4[3];
  uint4 o0, o1;
  o0.x = (u32)(a.x - gbase) | ((u32)(a.y - gbase) << 16);
  o0.y = (u32)(a.z - gbase) | ((u32)(a.w - gbase) << 16);
  o0.z = (u32)(b.x - gbase) | ((u32)(b.y - gbase) << 16);
  o0.w = (u32)(b.z - gbase) | ((u32)(b.w - gbase) << 16);
  o1.x = (u32)(c.x - gbase) | ((u32)(c.y - gbase) << 16);
  o1.y = (u32)(c.z - gbase) | ((u32)(c.w - gbase) << 16);
  o1.z = (u32)(d.x - gbase) | ((u32)(d.y - gbase) << 16);
  o1.w = (u32)(d.z - gbase) | ((u32)(d.w - gbase) << 16);
  uint4* op = (uint4*)(out + (size_t)node * DEG_);
  op[0] = o0; op[1] = o1;
}

__global__ __launch_bounds__(256) void k_prep_all(const int* __restrict__ src1,
    const int* __restrict__ src2, const float* __restrict__ W1,
    u16* __restrict__ lsrc1, u16* __restrict__ lsrc2, float* __restrict__ qb) {
  int blk = blockIdx.x;
  if (blk < 2245) {
    int node = blk * 256 + threadIdx.x;
    if (node < N1_) comp_idx<E1_>(src1, node, lsrc1);
  } else if (blk < 3368) {
    int node = (blk - 2245) * 256 + threadIdx.x;
    if (node < N2_) comp_idx<E2_>(src2, node, lsrc2);
  } else {
    int idx = (blk - 3368) * 256 + threadIdx.x;   // 4096 entries
    if (idx < 4096) {
      int e = idx & 3, rr = (idx >> 2) & 3, qq = (idx >> 4) & 7, oq = idx >> 7;
      int j = oq >> 3, c = (oq & 7) * 4 + rr, in = 4 * qq + e;
      float k0, k1, k2, k3;
      if (j == 0)      { k0 = 0.f; k1 = 0.f; k2 = 0.f;  k3 = -1.f / 6.f; }  // Q3
      else if (j == 1) { k0 = 0.f; k1 = 0.f; k2 = 0.5f; k3 = 1.5f; }        // Q2
      else if (j == 2) { k0 = 0.f; k1 = -1.f; k2 = -2.f; k3 = -3.f; }       // Q1
      else             { k0 = 1.f; k1 = 1.f; k2 = 1.f;  k3 = 1.f; }         // Q0
      const float* wp = W1 + in * 32 + c;
      qb[idx] = k0 * wp[0] + k1 * wp[1024] + k2 * wp[2048] + k3 * wp[3072];
    }
  }
}

// 1-channel gather over an LDS slab using u16 local indices.
#define GATHER1(dst, sv, si_, w4_)                                              \
  {                                                                             \
    uint4 A_ = si_[0], Bq_ = si_[1];                                            \
    float4 w_;                                                                  \
    w_ = w4_[0];                                                                \
    dst += w_.x * sv[A_.x & 0xFFFFu] + w_.y * sv[A_.x >> 16]                    \
         + w_.z * sv[A_.y & 0xFFFFu] + w_.w * sv[A_.y >> 16];                   \
    w_ = w4_[1];                                                                \
    dst += w_.x * sv[A_.z & 0xFFFFu] + w_.y * sv[A_.z >> 16]                    \
         + w_.z * sv[A_.w & 0xFFFFu] + w_.w * sv[A_.w >> 16];                   \
    w_ = w4_[2];                                                                \
    dst += w_.x * sv[Bq_.x & 0xFFFFu] + w_.y * sv[Bq_.x >> 16]                  \
         + w_.z * sv[Bq_.y & 0xFFFFu] + w_.w * sv[Bq_.y >> 16];                 \
    w_ = w4_[3];                                                                \
    dst += w_.x * sv[Bq_.z & 0xFFFFu] + w_.y * sv[Bq_.z >> 16]                  \
         + w_.z * sv[Bq_.w & 0xFFFFu] + w_.w * sv[Bq_.w >> 16];                 \
  }

// =====================================================================
// Layer 0: 512 threads, grid 1024 (64 graphs x 16 slices): 4 blocks/CU,
// 32 waves/CU.  ONLY delta vs the verified 470us build: the grid split
// (r8 bundled this with a register cap + remap + float moments and broke
// replay determinism; this takes the numerically-identical slicing alone).
// Slabs are L3-resident (2.3MB total) so doubled staging is free.
// =====================================================================
__global__ __launch_bounds__(512) void k0_mv1(const float* __restrict__ x,
    const u16* __restrict__ lsrc, const float* __restrict__ ew, float* __restrict__ T1) {
  __shared__ float sx[E1_];
  int g = blockIdx.x >> 4, q = blockIdx.x & 15;
  int gbase = g * E1_;
  for (int j = threadIdx.x; j < E1_; j += 512) sx[j] = x[gbase + j];
  __syncthreads();
  int start = q * SLC1_, end = min(start + SLC1_, E1_);
  for (int i = start + (int)threadIdx.x; i < end; i += 512) {
    int node = gbase + i;
    const uint4* si = (const uint4*)(lsrc + (size_t)node * DEG_);
    const float4* w4 = (const float4*)(ew + (size_t)node * DEG_);
    float acc = 0.f;
    GATHER1(acc, sx, si, w4);
    T1[node] = sx[i] - acc;   // T1 = x - L x
  }
}

__global__ __launch_bounds__(512) void k0_mv2(const float* __restrict__ x,
    const u16* __restrict__ lsrc, const float* __restrict__ ew,
    const float* __restrict__ T1, float* __restrict__ T2) {
  __shared__ float sT[E1_];
  int g = blockIdx.x >> 4, q = blockIdx.x & 15;
  int gbase = g * E1_;
  for (int j = threadIdx.x; j < E1_; j += 512) sT[j] = T1[gbase + j];
  __syncthreads();
  int start = q * SLC1_, end = min(start + SLC1_, E1_);
  for (int i = start + (int)threadIdx.x; i < end; i += 512) {
    int node = gbase + i;
    const uint4* si = (const uint4*)(lsrc + (size_t)node * DEG_);
    const float4* w4 = (const float4*)(ew + (size_t)node * DEG_);
    float acc = 0.f;
    GATHER1(acc, sT, si, w4);
    T2[node] = (3.f * sT[i] - acc - x[node]) * 0.5f;  // T2 = (3T1 - L T1 - T0)/2
  }
}

// T3 = (5T2 - L T2 - 2T1)/3, plus moment accumulation for layer-0 BN.
// Double partials, identical reduce structure to the verified build.
__global__ __launch_bounds__(512) void k0_mv3(const float* __restrict__ x,
    const u16* __restrict__ lsrc, const float* __restrict__ ew,
    const float* __restrict__ T1, const float* __restrict__ T2,
    float* __restrict__ T3, double* mom) {
  __shared__ float sT[E1_];
  __shared__ double sred[8 * 14];
  int g = blockIdx.x >> 4, q = blockIdx.x & 15;
  int gbase = g * E1_;
  for (int j = threadIdx.x; j < E1_; j += 512) sT[j] = T2[gbase + j];
  __syncthreads();
  double m[14];
#pragma unroll
  for (int j = 0; j < 14; ++j) m[j] = 0.0;
  int start = q * SLC1_, end = min(start + SLC1_, E1_);
  for (int i = start + (int)threadIdx.x; i < end; i += 512) {
    int node = gbase + i;
    const uint4* si = (const uint4*)(lsrc + (size_t)node * DEG_);
    const float4* w4 = (const float4*)(ew + (size_t)node * DEG_);
    float acc = 0.f;
    GATHER1(acc, sT, si, w4);
    float t1 = T1[node];
    float t2 = sT[i];
    float t3 = (5.f * t2 - acc - 2.f * t1) * (1.f / 3.f);
    T3[node] = t3;
    double d0 = x[node], d1 = t1, d2 = t2, d3 = t3;
    m[0] += d0; m[1] += d1; m[2] += d2; m[3] += d3;
    m[4] += d0 * d0; m[5] += d0 * d1; m[6] += d0 * d2; m[7] += d0 * d3;
    m[8] += d1 * d1; m[9] += d1 * d2; m[10] += d1 * d3;
    m[11] += d2 * d2; m[12] += d2 * d3; m[13] += d3 * d3;
  }
  int lane = threadIdx.x & 63, wid = threadIdx.x >> 6;
#pragma unroll
  for (int j = 0; j < 14; ++j) {
    double v = m[j];
    for (int o = 32; o; o >>= 1) v += __shfl_down(v, o);
    if (lane == 0) sred[wid * 14 + j] = v;
  }
  __syncthreads();
  if (threadIdx.x < 14) {
    double s = 0.0;
#pragma unroll
    for (int w = 0; w < 8; ++w) s += sred[w * 14 + threadIdx.x];
    atomicAdd(&mom[threadIdx.x], s);
  }
}

// BN params for layer 0; ALSO emits scW0[c*4+k] = scale0[c]*W0[k][c].
__global__ void k0_params(const double* __restrict__ mom, const float* __restrict__ W0,
    const float* __restrict__ g0, const float* __restrict__ be0,
    float* __restrict__ scale0, float* __restrict__ shiftE0, float* __restrict__ scW0) {
  int c = threadIdx.x;
  if (c >= 32) return;
  double inv = 1.0 / (double)N1_;
  double mm[4];
#pragma unroll
  for (int k = 0; k < 4; ++k) mm[k] = mom[k] * inv;
  double M[4][4];
  M[0][0] = mom[4] * inv;  M[0][1] = mom[5] * inv;  M[0][2] = mom[6] * inv;  M[0][3] = mom[7] * inv;
  M[1][1] = mom[8] * inv;  M[1][2] = mom[9] * inv;  M[1][3] = mom[10] * inv;
  M[2][2] = mom[11] * inv; M[2][3] = mom[12] * inv; M[3][3] = mom[13] * inv;
  M[1][0] = M[0][1]; M[2][0] = M[0][2]; M[3][0] = M[0][3];
  M[2][1] = M[1][2]; M[3][1] = M[1][3]; M[3][2] = M[2][3];
  double w[4];
#pragma unroll
  for (int k = 0; k < 4; ++k) w[k] = W0[k * 32 + c];
  double mean = 0.0;
#pragma unroll
  for (int k = 0; k < 4; ++k) mean += w[k] * mm[k];
  double e2 = 0.0;
#pragma unroll
  for (int k = 0; k < 4; ++k)
#pragma unroll
    for (int l = 0; l < 4; ++l) e2 += M[k][l] * w[k] * w[l];
  double var = e2 - mean * mean;
  double sc = (double)g0[c] / sqrt(var + EPS_);
  scale0[c] = (float)sc;
  shiftE0[c] = (float)((double)be0[c] - sc * mean);
#pragma unroll
  for (int k = 0; k < 4; ++k) scW0[c * 4 + k] = (float)(sc * w[k]);
}

// =====================================================================
// k_poolproj: FUSED pool + projection, 1 row/thread (proven).
// =====================================================================
__global__ __launch_bounds__(256) void k_poolproj(const float* __restrict__ x,
    const float* __restrict__ T1, const float* __restrict__ T2, const float* __restrict__ T3,
    const float* __restrict__ scW0, const float* __restrict__ shiftE0,
    const float* __restrict__ qb, float4* __restrict__ P4) {
  int r = blockIdx.x * 256 + threadIdx.x;
  if (r >= N2_) return;
  const float4* wt = (const float4*)scW0;   // wt[c] = scale0[c]*W0[0..3][c]
  float4 xr[8];
  {
    int b = r / E2_, j = r - b * E2_;
    int ga = b * E1_ + 2 * j;
    float2 xv = *(const float2*)(x + ga);
    float2 t1 = *(const float2*)(T1 + ga);
    float2 t2 = *(const float2*)(T2 + ga);
    float2 t3 = *(const float2*)(T3 + ga);
#pragma unroll
    for (int c8 = 0; c8 < 8; ++c8) {
      float4 o;
#pragma unroll
      for (int e = 0; e < 4; ++e) {
        int c = c8 * 4 + e;
        float4 w = wt[c];
        float sh = shiftE0[c];
        float da = w.x * xv.x + w.y * t1.x + w.z * t2.x + w.w * t3.x + sh;
        float db = w.x * xv.y + w.y * t1.y + w.z * t2.y + w.w * t3.y + sh;
        float v = fmaxf(lrelu(da), lrelu(db));
        if (e == 0) o.x = v; else if (e == 1) o.y = v; else if (e == 2) o.z = v; else o.w = v;
      }
      xr[c8] = o;
    }
  }
  const float4* qb4 = (const float4*)qb;
  for (int oq = 0; oq < 32; ++oq) {
    float4 acc = {0.f, 0.f, 0.f, 0.f};
#pragma unroll
    for (int qq = 0; qq < 8; ++qq) {
      const float4* wq = qb4 + (oq * 8 + qq) * 4;   // uniform address -> s_load
      float4 w0 = wq[0], w1 = wq[1], w2 = wq[2], w3 = wq[3];
      float4 xq = xr[qq];
      acc.x += dot4(xq, w0);
      acc.y += dot4(xq, w1);
      acc.z += dot4(xq, w2);
      acc.w += dot4(xq, w3);
    }
    P4[(size_t)oq * N2_ + r] = acc;
  }
}

// =====================================================================
// k1_chain: proven structure — unchanged.
// =====================================================================
__global__ __launch_bounds__(1024) void k1_chain(const float4* __restrict__ P4,
    float4* __restrict__ O4, const u16* __restrict__ lsrc,
    const float* __restrict__ ew, double* st) {
  __shared__ float4 bA[E2_], bB[E2_];   // 2 x 71,824 B
  __shared__ float sacc[8];
  int v = (blockIdx.x & 7) * 64 + (blockIdx.x >> 3);   // XCD-contiguous graphs
  int g = v >> 3, cg = v & 7;
  int gbase = g * E2_;
  int tid = threadIdx.x;
  if (tid < 8) sacc[tid] = 0.f;
  {
    const float4* sp = P4 + (size_t)cg * N2_ + gbase;   // P3 plane slab
    for (int i = tid; i < E2_; i += 1024) bA[i] = sp[i];
  }
  float4* cur = bA;
  float4* nxt = bB;
  for (int s = 1; s <= 3; ++s) {
    __syncthreads();
    const float4* selfp = P4 + (size_t)(s * 8 + cg) * N2_ + gbase;
    for (int n = tid; n < E2_; n += 1024) {
      const uint4* si = (const uint4*)(lsrc + (size_t)(gbase + n) * DEG_);
      const float4* w4 = (const float4*)(ew + (size_t)(gbase + n) * DEG_);
      uint4 A = si[0], Bq = si[1];
      float4 acc = selfp[n];
      float4 w;
      w = w4[0];
      gacc(acc, w.x, cur[A.x & 0xFFFFu]); gacc(acc, w.y, cur[A.x >> 16]);
      gacc(acc, w.z, cur[A.y & 0xFFFFu]); gacc(acc, w.w, cur[A.y >> 16]);
      w = w4[1];
      gacc(acc, w.x, cur[A.z & 0xFFFFu]); gacc(acc, w.y, cur[A.z >> 16]);
      gacc(acc, w.z, cur[A.w & 0xFFFFu]); gacc(acc, w.w, cur[A.w >> 16]);
      w = w4[2];
      gacc(acc, w.x, cur[Bq.x & 0xFFFFu]); gacc(acc, w.y, cur[Bq.x >> 16]);
      gacc(acc, w.z, cur[Bq.y & 0xFFFFu]); gacc(acc, w.w, cur[Bq.y >> 16]);
      w = w4[3];
      gacc(acc, w.x, cur[Bq.z & 0xFFFFu]); gacc(acc, w.y, cur[Bq.z >> 16]);
      gacc(acc, w.z, cur[Bq.w & 0xFFFFu]); gacc(acc, w.w, cur[Bq.w >> 16]);
      nxt[n] = acc;
    }
    float4* t = cur; cur = nxt; nxt = t;
  }
  __syncthreads();
  float4* op = O4 + (size_t)cg * N2_ + gbase;   // over P3 plane: disjoint per (g,cg)
  float4 s1 = {0.f, 0.f, 0.f, 0.f}, s2 = {0.f, 0.f, 0.f, 0.f};
  for (int n = tid; n < E2_; n += 1024) {
    float4 vv = cur[n];
    op[n] = vv;
    s1.x += vv.x; s1.y += vv.y; s1.z += vv.z; s1.w += vv.w;
    s2.x += vv.x * vv.x; s2.y += vv.y * vv.y; s2.z += vv.z * vv.z; s2.w += vv.w * vv.w;
  }
  for (int o = 32; o; o >>= 1) {
    s1.x += __shfl_down(s1.x, o); s1.y += __shfl_down(s1.y, o);
    s1.z += __shfl_down(s1.z, o); s1.w += __shfl_down(s1.w, o);
    s2.x += __shfl_down(s2.x, o); s2.y += __shfl_down(s2.y, o);
    s2.z += __shfl_down(s2.z, o); s2.w += __shfl_down(s2.w, o);
  }
  if ((tid & 63) == 0) {
    atomicAdd(&sacc[0], s1.x); atomicAdd(&sacc[1], s1.y);
    atomicAdd(&sacc[2], s1.z); atomicAdd(&sacc[3], s1.w);
    atomicAdd(&sacc[4], s2.x); atomicAdd(&sacc[5], s2.y);
    atomicAdd(&sacc[6], s2.z); atomicAdd(&sacc[7], s2.w);
  }
  __syncthreads();
  if (tid < 4) {
    int ch = cg * 4 + tid;
    atomicAdd(&st[ch], (double)sacc[tid]);
    atomicAdd(&st[32 + ch], (double)sacc[4 + tid]);
  }
}

__global__ void k1_params(const double* __restrict__ sum, const double* __restrict__ sq,
    const float* __restrict__ g1, const float* __restrict__ be1,
    float* __restrict__ scale1, float* __restrict__ shiftE1) {
  int c = threadIdx.x;
  if (c >= 32) return;
  double mean = sum[c] / (double)N2_;
  double var = sq[c] / (double)N2_ - mean * mean;
  double sc = (double)g1[c] / sqrt(var + EPS_);
  scale1[c] = (float)sc;
  shiftE1[c] = (float)((double)be1[c] - sc * mean);
}

// =====================================================================
// Layer-2 Horner on 1-channel fields.
// =====================================================================
__global__ __launch_bounds__(256) void k2_proj(const float* __restrict__ X,
    const float* __restrict__ W2, const float* __restrict__ scale1,
    const float* __restrict__ shiftE1,
    float* __restrict__ u0, float* __restrict__ u1,
    float* __restrict__ u2, float* __restrict__ u3) {
  __shared__ float qv[4][32];
  __shared__ float fsc[32], fsh[32];
  int tid = threadIdx.x;
  if (tid < 128) {
    int cp = tid & 31, j = tid >> 5;
    float w0 = W2[cp], w1 = W2[32 + cp], w2 = W2[64 + cp], w3 = W2[96 + cp];
    float q;
    if (j == 0)      q = w0 + w1 + w2 + w3;
    else if (j == 1) q = -w1 - 2.f * w2 - 3.f * w3;
    else if (j == 2) q = 0.5f * w2 + 1.5f * w3;
    else             q = -w3 * (1.f / 6.f);
    qv[j][cp] = q;
  }
  if (tid < 32) { fsc[tid] = scale1[tid]; fsh[tid] = shiftE1[tid]; }
  __syncthreads();
  int node = blockIdx.x * 256 + tid;
  if (node >= N2_) return;
  const float4* xf = (const float4*)X;
  float a0 = 0.f, a1 = 0.f, a2 = 0.f, a3 = 0.f;
#pragma unroll
  for (int t = 0; t < 8; ++t) {
    float4 v = xf[(size_t)t * N2_ + node];
    float f0 = lrelu(fsc[4 * t] * v.x + fsh[4 * t]);
    float f1 = lrelu(fsc[4 * t + 1] * v.y + fsh[4 * t + 1]);
    float f2_ = lrelu(fsc[4 * t + 2] * v.z + fsh[4 * t + 2]);
    float f3 = lrelu(fsc[4 * t + 3] * v.w + fsh[4 * t + 3]);
    a0 += f0 * qv[0][4 * t] + f1 * qv[0][4 * t + 1] + f2_ * qv[0][4 * t + 2] + f3 * qv[0][4 * t + 3];
    a1 += f0 * qv[1][4 * t] + f1 * qv[1][4 * t + 1] + f2_ * qv[1][4 * t + 2] + f3 * qv[1][4 * t + 3];
    a2 += f0 * qv[2][4 * t] + f1 * qv[2][4 * t + 1] + f2_ * qv[2][4 * t + 2] + f3 * qv[2][4 * t + 3];
    a3 += f0 * qv[3][4 * t] + f1 * qv[3][4 * t + 1] + f2_ * qv[3][4 * t + 2] + f3 * qv[3][4 * t + 3];
  }
  u0[node] = a0; u1[node] = a1; u2[node] = a2; u3[node] = a3;
}

// k2_step: 512 threads, grid 1024 (64 graphs x 16 slices): 4 blocks/CU.
__global__ __launch_bounds__(512) void k2_step(const float* __restrict__ z,
    const u16* __restrict__ lsrc, const float* __restrict__ ew,
    const float* __restrict__ u, float* __restrict__ zo,
    int do_stats, double* st2) {
  __shared__ float sz[E2_];
  __shared__ double sred[8][2];
  int g = blockIdx.x >> 4, q = blockIdx.x & 15;
  int gbase = g * E2_;
  for (int j = threadIdx.x; j < E2_; j += 512) sz[j] = z[gbase + j];
  __syncthreads();
  int start = q * SLC2_, end = min(start + SLC2_, E2_);
  double aS = 0.0, aQ = 0.0;
  for (int i = start + (int)threadIdx.x; i < end; i += 512) {
    int node = gbase + i;
    const uint4* si = (const uint4*)(lsrc + (size_t)node * DEG_);
    const float4* w4 = (const float4*)(ew + (size_t)node * DEG_);
    float acc = 0.f;
    GATHER1(acc, sz, si, w4);
    float val = u[node] + acc;
    zo[node] = val;
    if (do_stats) { aS += val; aQ += (double)val * (double)val; }
  }
  if (do_stats) {
    int lane = threadIdx.x & 63, wid = threadIdx.x >> 6;
    for (int o = 32; o; o >>= 1) { aS += __shfl_down(aS, o); aQ += __shfl_down(aQ, o); }
    if (lane == 0) { sred[wid][0] = aS; sred[wid][1] = aQ; }
    __syncthreads();
    if (threadIdx.x == 0) {
      double s = 0.0, qq = 0.0;
#pragma unroll
      for (int w = 0; w < 8; ++w) { s += sred[w][0]; qq += sred[w][1]; }
      atomicAdd(&st2[0], s); atomicAdd(&st2[1], qq);
    }
  }
}

__global__ void k2_params(const double* __restrict__ st2, const float* __restrict__ g2,
    const float* __restrict__ be2, float* __restrict__ p /* [128]=scale2 [129]=shiftE2 */) {
  if (threadIdx.x != 0) return;
  double mean = st2[0] / (double)N2_;
  double var = st2[1] / (double)N2_ - mean * mean;
  double sc = (double)g2[0] / sqrt(var + EPS_);
  p[128] = (float)sc;
  p[129] = (float)((double)be2[0] - sc * mean);
}

// MLP gemm1: 8 batches/block x 32 row-pieces, grid 256.
__global__ __launch_bounds__(256) void k3_gemm1(const float* __restrict__ out2,
    const float* __restrict__ lin1W, const float* __restrict__ p, float* h1pre) {
  __shared__ float f2v[8][144];
  float sc = p[128], sh = p[129];
  int bs = blockIdx.x & 7, rs = blockIdx.x >> 3;
  int b0 = bs * 8;
  int r0 = rs * 141;
  int nr = min(141, E2_ - r0);
  int c = threadIdx.x;
#pragma unroll
  for (int b = 0; b < 8; ++b)
    for (int j = c; j < 144; j += 256)
      f2v[b][j] = (j < nr) ? lrelu(sc * out2[(b0 + b) * E2_ + r0 + j] + sh) : 0.f;
  __syncthreads();
  float acc[8];
#pragma unroll
  for (int b = 0; b < 8; ++b) acc[b] = 0.f;
  int nr4 = nr & ~3;
  int j = 0;
  for (; j < nr4; j += 4) {
    const float* wp = lin1W + (size_t)(r0 + j) * 256 + c;
    float w0 = wp[0], w1 = wp[256], w2 = wp[512], w3 = wp[768];
#pragma unroll
    for (int b = 0; b < 8; ++b) {
      float4 f = *(const float4*)&f2v[b][j];
      acc[b] += f.x * w0 + f.y * w1 + f.z * w2 + f.w * w3;
    }
  }
  for (; j < nr; ++j) {
    float w = lin1W[(size_t)(r0 + j) * 256 + c];
#pragma unroll
    for (int b = 0; b < 8; ++b) acc[b] += f2v[b][j] * w;
  }
#pragma unroll
  for (int b = 0; b < 8; ++b)
    atomicAdd(&h1pre[(b0 + b) * 256 + c], acc[b]);
}

// =====================================================================
// k5_gemm2bn: FUSED BN1+ReLU+gemm2.
// =====================================================================
__global__ __launch_bounds__(256) void k5_gemm2bn(const float* __restrict__ h1pre,
    const float* __restrict__ g, const float* __restrict__ be,
    const float* __restrict__ lin2W, float* __restrict__ h2pre) {
  __shared__ float sh1[64 * 257];
  __shared__ float sred[256];
  int c = blockIdx.x;
  int tid = threadIdx.x;
  for (int i = tid; i < 64 * 256; i += 256) {
    int b = i >> 8, cc = i & 255;
    sh1[b * 257 + cc] = h1pre[i];
  }
  __syncthreads();
  {
    int cc = tid;
    double s = 0.0, qd = 0.0;
    float vs[64];
#pragma unroll
    for (int b = 0; b < 64; ++b) { float v = sh1[b * 257 + cc]; vs[b] = v; s += v; qd += (double)v * v; }
    double mean = s / 64.0, var = qd / 64.0 - mean * mean;
    double scd = (double)g[cc] / sqrt(var + EPS_);
    double shd = (double)be[cc] - scd * mean;
#pragma unroll
    for (int b = 0; b < 64; ++b) {
      float y = (float)(scd * vs[b] + shd);
      sh1[b * 257 + cc] = y > 0.f ? y : 0.f;
    }
  }
  __syncthreads();
  int b = tid & 63, q = tid >> 6;
  float acc = 0.f;
  for (int r = q; r < 256; r += 4) acc += sh1[b * 257 + r] * lin2W[r * 128 + c];
  sred[tid] = acc;
  __syncthreads();
  if (tid < 64)
    h2pre[tid * 128 + c] = sred[tid] + sred[64 + tid] + sred[128 + tid] + sred[192 + tid];
}

// BN2 + ReLU + final linear -> out[64]
__global__ __launch_bounds__(256) void k6_final(const float* __restrict__ h2pre,
    const float* __restrict__ g, const float* __restrict__ be,
    const float* __restrict__ W3, const float* __restrict__ b3, float* __restrict__ outp) {
  __shared__ float sh2[64 * 129];
  __shared__ float sred[256];
  int tid = threadIdx.x;
  if (tid < 128) {
    int c = tid;
    float vs[64];
    double s = 0.0, q = 0.0;
    for (int b = 0; b < 64; ++b) { float v = h2pre[b * 128 + c]; vs[b] = v; s += v; q += (double)v * v; }
    double mean = s / 64.0, var = q / 64.0 - mean * mean;
    double scd = (double)g[c] / sqrt(var + EPS_);
    double shd = (double)be[c] - scd * mean;
    for (int b = 0; b < 64; ++b) {
      float y = (float)(scd * vs[b] + shd);
      sh2[b * 129 + c] = y > 0.f ? y : 0.f;
    }
  }
  __syncthreads();
  int b = tid & 63, q = tid >> 6;
  float acc = 0.f;
  for (int r = q; r < 128; r += 4) acc += sh2[b * 129 + r] * W3[r];
  sred[tid] = acc;
  __syncthreads();
  if (tid < 64)
    outp[tid] = sred[tid] + sred[64 + tid] + sred[128 + tid] + sred[192 + tid] + b3[0];
}

// =====================================================================
extern "C" void kernel_launch(void* const* d_in, const int* in_sizes, int n_in,
                              void* d_out, int out_size, void* d_ws, size_t ws_size,
                              hipStream_t stream) {
  const float* x    = (const float*)d_in[0];
  const int*   ei1  = (const int*)d_in[1];
  const float* ew1  = (const float*)d_in[2];
  const int*   ei2  = (const int*)d_in[3];
  const float* ew2  = (const float*)d_in[4];
  const float* W0   = (const float*)d_in[5];
  const float* g0   = (const float*)d_in[7];
  const float* be0  = (const float*)d_in[8];
  const float* W1   = (const float*)d_in[9];
  const float* g1   = (const float*)d_in[11];
  const float* be1  = (const float*)d_in[12];
  const float* W2   = (const float*)d_in[13];
  const float* g2   = (const float*)d_in[15];
  const float* be2  = (const float*)d_in[16];
  const float* lin1W = (const float*)d_in[17];
  const float* bn1g = (const float*)d_in[19];
  const float* bn1b = (const float*)d_in[20];
  const float* lin2W = (const float*)d_in[21];
  const float* bn2g = (const float*)d_in[23];
  const float* bn2b = (const float*)d_in[24];
  const float* lin3W = (const float*)d_in[25];
  const float* lin3b = (const float*)d_in[26];

  char* ws = (char*)d_ws;
  double* stats  = (double*)ws;                 // [0..13] mom0, [14..45] s1sum, [46..77] s1sq, [78..79] st2
  float*  params = (float*)(ws + 1024);         // [0..31] scale0, [32..63] shiftE0, [64..95] scale1,
                                                // [96..127] shiftE1, [128..129] scale2/shift2, [160..287] scW0
  float*  h1pre  = (float*)(ws + 4096);
  float*  h2pre  = (float*)(ws + 4096 + 131072);
  float*  qb     = (float*)(ws + 196608);       // 4096 floats combined Q weights
  float*  Treg   = (float*)(ws + 262144);
  float* T1_0 = Treg;
  float* T2_0 = Treg + N1_;
  float* T3_0 = Treg + 2 * (size_t)N1_;
  float* u0   = Treg;                           // overlays (T dead after k_poolproj)
  float* u1   = Treg + (size_t)N2_;
  float* u2   = Treg + 2 * (size_t)N2_;
  float* u3   = Treg + 3 * (size_t)N2_;
  float* zA   = Treg + 4 * (size_t)N2_;
  float* out2 = Treg + 5 * (size_t)N2_;         // 6*N2 <= 3*N1  ✓
  float*  big = (float*)(ws + 262144 + 3 * (size_t)N1_ * 4);
  float* bufA = big;                            // hosts lsrc2 (x1 eliminated)
  float* Pbuf = big + 32 * (size_t)N2_;         // 32 planes x N2 float4
  u16* lsrc1 = (u16*)Pbuf;                      // consumed by mv1..3 before Pbuf written
  u16* lsrc2 = (u16*)bufA;

  hipMemsetAsync(stats, 0, 80 * sizeof(double), stream);
  hipMemsetAsync(h1pre, 0, 65536, stream);

  // ---- merged prep: lsrc1 | lsrc2 | qb ----
  k_prep_all<<<3384, 256, 0, stream>>>(ei1, ei2, W1, lsrc1, lsrc2, qb);

  // ---- layer 0 (16 slices/graph: 4 blocks/CU) ----
  k0_mv1<<<1024, 512, 0, stream>>>(x, lsrc1, ew1, T1_0);
  k0_mv2<<<1024, 512, 0, stream>>>(x, lsrc1, ew1, T1_0, T2_0);
  k0_mv3<<<1024, 512, 0, stream>>>(x, lsrc1, ew1, T1_0, T2_0, T3_0, stats);
  k0_params<<<1, 32, 0, stream>>>(stats, W0, g0, be0, params, params + 32, params + 160);

  // ---- fused pool + projection to 32 planes (1 row/thread) ----
  k_poolproj<<<(N2_ + 255) / 256, 256, 0, stream>>>(x, T1_0, T2_0, T3_0,
                                                    params + 160, params + 32, qb, (float4*)Pbuf);

  // ---- layer 1 chain ----
  k1_chain<<<512, 1024, 0, stream>>>((const float4*)Pbuf, (float4*)Pbuf, lsrc2, ew2, stats + 14);
  k1_params<<<1, 32, 0, stream>>>(stats + 14, stats + 46, g1, be1, params + 64, params + 96);

  // ---- layer 2 (Horner, 1-channel; out1 = planes 0..7 of Pbuf) ----
  k2_proj<<<(N2_ + 255) / 256, 256, 0, stream>>>(Pbuf, W2, params + 64, params + 96,
                                                 u0, u1, u2, u3);
  k2_step<<<1024, 512, 0, stream>>>(u3, lsrc2, ew2, u2, zA, 0, nullptr);       // zA = u2 + L u3
  k2_step<<<1024, 512, 0, stream>>>(zA, lsrc2, ew2, u1, u3, 0, nullptr);       // u3slot = u1 + L zA
  k2_step<<<1024, 512, 0, stream>>>(u3, lsrc2, ew2, u0, out2, 1, stats + 78);  // out2 + stats
  k2_params<<<1, 64, 0, stream>>>(stats + 78, g2, be2, params);

  // ---- MLP head ----
  k3_gemm1<<<256, 256, 0, stream>>>(out2, lin1W, params, h1pre);
  k5_gemm2bn<<<128, 256, 0, stream>>>(h1pre, bn1g, bn1b, lin2W, h2pre);
  k6_final<<<1, 256, 0, stream>>>(h2pre, bn2g, bn2b, lin3W, lin3b, (float*)d_out);
}

// Round 12
// 470.116 us; speedup vs baseline: 1.0372x; 1.0372x over previous
//
#include <hip/hip_runtime.h>
#include <cstdint>

#define SLOPE 0.33f

static constexpr int B_   = 64;
static constexpr int E1_  = 8978;
static constexpr int E2_  = 4489;
static constexpr int N1_  = B_ * E1_;      // 574592
static constexpr int N2_  = B_ * E2_;      // 287296
static constexpr int DEG_ = 16;
static constexpr int SLC1_ = 1123;         // ceil(E1_/8)
static constexpr int SLC2_ = 562;          // ceil(E2_/8)
static constexpr double EPS_ = 1e-5;

typedef unsigned short u16;
typedef unsigned int   u32;

__device__ __forceinline__ float lrelu(float v) { return v > 0.f ? v : SLOPE * v; }
__device__ __forceinline__ float dot4(float4 a, float4 b) {
  return a.x * b.x + a.y * b.y + a.z * b.z + a.w * b.w;
}
__device__ __forceinline__ void gacc(float4& acc, float wgt, const float4& gv) {
  acc.x += wgt * gv.x; acc.y += wgt * gv.y; acc.z += wgt * gv.z; acc.w += wgt * gv.w;
}

// ---------------------------------------------------------------------
// merged prep: lsrc1 (2245 blocks) | lsrc2 (1123 blocks) | qb (16 blocks)
// ---------------------------------------------------------------------
template<int NPG>
__device__ __forceinline__ void comp_idx(const int* __restrict__ src, int node,
    u16* __restrict__ out) {
  int gbase = (node / NPG) * NPG;
  const int4* s4 = (const int4*)(src + (size_t)node * DEG_);
  int4 a = s4[0], b = s4[1], c = s4[2], d = s4[3];
  uint4 o0, o1;
  o0.x = (u32)(a.x - gbase) | ((u32)(a.y - gbase) << 16);
  o0.y = (u32)(a.z - gbase) | ((u32)(a.w - gbase) << 16);
  o0.z = (u32)(b.x - gbase) | ((u32)(b.y - gbase) << 16);
  o0.w = (u32)(b.z - gbase) | ((u32)(b.w - gbase) << 16);
  o1.x = (u32)(c.x - gbase) | ((u32)(c.y - gbase) << 16);
  o1.y = (u32)(c.z - gbase) | ((u32)(c.w - gbase) << 16);
  o1.z = (u32)(d.x - gbase) | ((u32)(d.y - gbase) << 16);
  o1.w = (u32)(d.z - gbase) | ((u32)(d.w - gbase) << 16);
  uint4* op = (uint4*)(out + (size_t)node * DEG_);
  op[0] = o0; op[1] = o1;
}

__global__ __launch_bounds__(256) void k_prep_all(const int* __restrict__ src1,
    const int* __restrict__ src2, const float* __restrict__ W1,
    u16* __restrict__ lsrc1, u16* __restrict__ lsrc2, float* __restrict__ qb) {
  int blk = blockIdx.x;
  if (blk < 2245) {
    int node = blk * 256 + threadIdx.x;
    if (node < N1_) comp_idx<E1_>(src1, node, lsrc1);
  } else if (blk < 3368) {
    int node = (blk - 2245) * 256 + threadIdx.x;
    if (node < N2_) comp_idx<E2_>(src2, node, lsrc2);
  } else {
    int idx = (blk - 3368) * 256 + threadIdx.x;   // 4096 entries
    if (idx < 4096) {
      int e = idx & 3, rr = (idx >> 2) & 3, qq = (idx >> 4) & 7, oq = idx >> 7;
      int j = oq >> 3, c = (oq & 7) * 4 + rr, in = 4 * qq + e;
      float k0, k1, k2, k3;
      if (j == 0)      { k0 = 0.f; k1 = 0.f; k2 = 0.f;  k3 = -1.f / 6.f; }  // Q3
      else if (j == 1) { k0 = 0.f; k1 = 0.f; k2 = 0.5f; k3 = 1.5f; }        // Q2
      else if (j == 2) { k0 = 0.f; k1 = -1.f; k2 = -2.f; k3 = -3.f; }       // Q1
      else             { k0 = 1.f; k1 = 1.f; k2 = 1.f;  k3 = 1.f; }         // Q0
      const float* wp = W1 + in * 32 + c;
      qb[idx] = k0 * wp[0] + k1 * wp[1024] + k2 * wp[2048] + k3 * wp[3072];
    }
  }
}

// 1-channel gather over an LDS slab using u16 local indices.
#define GATHER1(dst, sv, si_, w4_)                                              \
  {                                                                             \
    uint4 A_ = si_[0], Bq_ = si_[1];                                            \
    float4 w_;                                                                  \
    w_ = w4_[0];                                                                \
    dst += w_.x * sv[A_.x & 0xFFFFu] + w_.y * sv[A_.x >> 16]                    \
         + w_.z * sv[A_.y & 0xFFFFu] + w_.w * sv[A_.y >> 16];                   \
    w_ = w4_[1];                                                                \
    dst += w_.x * sv[A_.z & 0xFFFFu] + w_.y * sv[A_.z >> 16]                    \
         + w_.z * sv[A_.w & 0xFFFFu] + w_.w * sv[A_.w >> 16];                   \
    w_ = w4_[2];                                                                \
    dst += w_.x * sv[Bq_.x & 0xFFFFu] + w_.y * sv[Bq_.x >> 16]                  \
         + w_.z * sv[Bq_.y & 0xFFFFu] + w_.w * sv[Bq_.y >> 16];                 \
    w_ = w4_[3];                                                                \
    dst += w_.x * sv[Bq_.z & 0xFFFFu] + w_.y * sv[Bq_.z >> 16]                  \
         + w_.z * sv[Bq_.w & 0xFFFFu] + w_.w * sv[Bq_.w >> 16];                 \
  }

// =====================================================================
// Layer 0: 512 threads, grid 512 (64 graphs x 8 slices): 2 blocks/CU.
// (r11 A/B: 16-slice split regressed +17us — gathers are TA/L2-pipe
// bound, not wave-starved; 8 slices is the verified optimum.)
// =====================================================================
__global__ __launch_bounds__(512) void k0_mv1(const float* __restrict__ x,
    const u16* __restrict__ lsrc, const float* __restrict__ ew, float* __restrict__ T1) {
  __shared__ float sx[E1_];
  int g = blockIdx.x >> 3, q = blockIdx.x & 7;
  int gbase = g * E1_;
  for (int j = threadIdx.x; j < E1_; j += 512) sx[j] = x[gbase + j];
  __syncthreads();
  int start = q * SLC1_, end = min(start + SLC1_, E1_);
  for (int i = start + (int)threadIdx.x; i < end; i += 512) {
    int node = gbase + i;
    const uint4* si = (const uint4*)(lsrc + (size_t)node * DEG_);
    const float4* w4 = (const float4*)(ew + (size_t)node * DEG_);
    float acc = 0.f;
    GATHER1(acc, sx, si, w4);
    T1[node] = sx[i] - acc;   // T1 = x - L x
  }
}

__global__ __launch_bounds__(512) void k0_mv2(const float* __restrict__ x,
    const u16* __restrict__ lsrc, const float* __restrict__ ew,
    const float* __restrict__ T1, float* __restrict__ T2) {
  __shared__ float sT[E1_];
  int g = blockIdx.x >> 3, q = blockIdx.x & 7;
  int gbase = g * E1_;
  for (int j = threadIdx.x; j < E1_; j += 512) sT[j] = T1[gbase + j];
  __syncthreads();
  int start = q * SLC1_, end = min(start + SLC1_, E1_);
  for (int i = start + (int)threadIdx.x; i < end; i += 512) {
    int node = gbase + i;
    const uint4* si = (const uint4*)(lsrc + (size_t)node * DEG_);
    const float4* w4 = (const float4*)(ew + (size_t)node * DEG_);
    float acc = 0.f;
    GATHER1(acc, sT, si, w4);
    T2[node] = (3.f * sT[i] - acc - x[node]) * 0.5f;  // T2 = (3T1 - L T1 - T0)/2
  }
}

// T3 = (5T2 - L T2 - 2T1)/3, plus moment accumulation for layer-0 BN.
__global__ __launch_bounds__(512) void k0_mv3(const float* __restrict__ x,
    const u16* __restrict__ lsrc, const float* __restrict__ ew,
    const float* __restrict__ T1, const float* __restrict__ T2,
    float* __restrict__ T3, double* mom) {
  __shared__ float sT[E1_];
  __shared__ double sred[8 * 14];
  int g = blockIdx.x >> 3, q = blockIdx.x & 7;
  int gbase = g * E1_;
  for (int j = threadIdx.x; j < E1_; j += 512) sT[j] = T2[gbase + j];
  __syncthreads();
  double m[14];
#pragma unroll
  for (int j = 0; j < 14; ++j) m[j] = 0.0;
  int start = q * SLC1_, end = min(start + SLC1_, E1_);
  for (int i = start + (int)threadIdx.x; i < end; i += 512) {
    int node = gbase + i;
    const uint4* si = (const uint4*)(lsrc + (size_t)node * DEG_);
    const float4* w4 = (const float4*)(ew + (size_t)node * DEG_);
    float acc = 0.f;
    GATHER1(acc, sT, si, w4);
    float t1 = T1[node];
    float t2 = sT[i];
    float t3 = (5.f * t2 - acc - 2.f * t1) * (1.f / 3.f);
    T3[node] = t3;
    double d0 = x[node], d1 = t1, d2 = t2, d3 = t3;
    m[0] += d0; m[1] += d1; m[2] += d2; m[3] += d3;
    m[4] += d0 * d0; m[5] += d0 * d1; m[6] += d0 * d2; m[7] += d0 * d3;
    m[8] += d1 * d1; m[9] += d1 * d2; m[10] += d1 * d3;
    m[11] += d2 * d2; m[12] += d2 * d3; m[13] += d3 * d3;
  }
  int lane = threadIdx.x & 63, wid = threadIdx.x >> 6;
#pragma unroll
  for (int j = 0; j < 14; ++j) {
    double v = m[j];
    for (int o = 32; o; o >>= 1) v += __shfl_down(v, o);
    if (lane == 0) sred[wid * 14 + j] = v;
  }
  __syncthreads();
  if (threadIdx.x < 14) {
    double s = 0.0;
#pragma unroll
    for (int w = 0; w < 8; ++w) s += sred[w * 14 + threadIdx.x];
    atomicAdd(&mom[threadIdx.x], s);
  }
}

// BN params for layer 0; ALSO emits scW0[c*4+k] = scale0[c]*W0[k][c].
__global__ void k0_params(const double* __restrict__ mom, const float* __restrict__ W0,
    const float* __restrict__ g0, const float* __restrict__ be0,
    float* __restrict__ scale0, float* __restrict__ shiftE0, float* __restrict__ scW0) {
  int c = threadIdx.x;
  if (c >= 32) return;
  double inv = 1.0 / (double)N1_;
  double mm[4];
#pragma unroll
  for (int k = 0; k < 4; ++k) mm[k] = mom[k] * inv;
  double M[4][4];
  M[0][0] = mom[4] * inv;  M[0][1] = mom[5] * inv;  M[0][2] = mom[6] * inv;  M[0][3] = mom[7] * inv;
  M[1][1] = mom[8] * inv;  M[1][2] = mom[9] * inv;  M[1][3] = mom[10] * inv;
  M[2][2] = mom[11] * inv; M[2][3] = mom[12] * inv; M[3][3] = mom[13] * inv;
  M[1][0] = M[0][1]; M[2][0] = M[0][2]; M[3][0] = M[0][3];
  M[2][1] = M[1][2]; M[3][1] = M[1][3]; M[3][2] = M[2][3];
  double w[4];
#pragma unroll
  for (int k = 0; k < 4; ++k) w[k] = W0[k * 32 + c];
  double mean = 0.0;
#pragma unroll
  for (int k = 0; k < 4; ++k) mean += w[k] * mm[k];
  double e2 = 0.0;
#pragma unroll
  for (int k = 0; k < 4; ++k)
#pragma unroll
    for (int l = 0; l < 4; ++l) e2 += M[k][l] * w[k] * w[l];
  double var = e2 - mean * mean;
  double sc = (double)g0[c] / sqrt(var + EPS_);
  scale0[c] = (float)sc;
  shiftE0[c] = (float)((double)be0[c] - sc * mean);
#pragma unroll
  for (int k = 0; k < 4; ++k) scW0[c * 4 + k] = (float)(sc * w[k]);
}

// =====================================================================
// k_poolproj: FUSED pool + projection, 1 row/thread (proven).
// =====================================================================
__global__ __launch_bounds__(256) void k_poolproj(const float* __restrict__ x,
    const float* __restrict__ T1, const float* __restrict__ T2, const float* __restrict__ T3,
    const float* __restrict__ scW0, const float* __restrict__ shiftE0,
    const float* __restrict__ qb, float4* __restrict__ P4) {
  int r = blockIdx.x * 256 + threadIdx.x;
  if (r >= N2_) return;
  const float4* wt = (const float4*)scW0;   // wt[c] = scale0[c]*W0[0..3][c]
  float4 xr[8];
  {
    int b = r / E2_, j = r - b * E2_;
    int ga = b * E1_ + 2 * j;
    float2 xv = *(const float2*)(x + ga);
    float2 t1 = *(const float2*)(T1 + ga);
    float2 t2 = *(const float2*)(T2 + ga);
    float2 t3 = *(const float2*)(T3 + ga);
#pragma unroll
    for (int c8 = 0; c8 < 8; ++c8) {
      float4 o;
#pragma unroll
      for (int e = 0; e < 4; ++e) {
        int c = c8 * 4 + e;
        float4 w = wt[c];
        float sh = shiftE0[c];
        float da = w.x * xv.x + w.y * t1.x + w.z * t2.x + w.w * t3.x + sh;
        float db = w.x * xv.y + w.y * t1.y + w.z * t2.y + w.w * t3.y + sh;
        float v = fmaxf(lrelu(da), lrelu(db));
        if (e == 0) o.x = v; else if (e == 1) o.y = v; else if (e == 2) o.z = v; else o.w = v;
      }
      xr[c8] = o;
    }
  }
  const float4* qb4 = (const float4*)qb;
  for (int oq = 0; oq < 32; ++oq) {
    float4 acc = {0.f, 0.f, 0.f, 0.f};
#pragma unroll
    for (int qq = 0; qq < 8; ++qq) {
      const float4* wq = qb4 + (oq * 8 + qq) * 4;   // uniform address -> s_load
      float4 w0 = wq[0], w1 = wq[1], w2 = wq[2], w3 = wq[3];
      float4 xq = xr[qq];
      acc.x += dot4(xq, w0);
      acc.y += dot4(xq, w1);
      acc.z += dot4(xq, w2);
      acc.w += dot4(xq, w3);
    }
    P4[(size_t)oq * N2_ + r] = acc;
  }
}

// =====================================================================
// k1_chain: proven structure — unchanged.
// =====================================================================
__global__ __launch_bounds__(1024) void k1_chain(const float4* __restrict__ P4,
    float4* __restrict__ O4, const u16* __restrict__ lsrc,
    const float* __restrict__ ew, double* st) {
  __shared__ float4 bA[E2_], bB[E2_];   // 2 x 71,824 B
  __shared__ float sacc[8];
  int v = (blockIdx.x & 7) * 64 + (blockIdx.x >> 3);   // XCD-contiguous graphs
  int g = v >> 3, cg = v & 7;
  int gbase = g * E2_;
  int tid = threadIdx.x;
  if (tid < 8) sacc[tid] = 0.f;
  {
    const float4* sp = P4 + (size_t)cg * N2_ + gbase;   // P3 plane slab
    for (int i = tid; i < E2_; i += 1024) bA[i] = sp[i];
  }
  float4* cur = bA;
  float4* nxt = bB;
  for (int s = 1; s <= 3; ++s) {
    __syncthreads();
    const float4* selfp = P4 + (size_t)(s * 8 + cg) * N2_ + gbase;
    for (int n = tid; n < E2_; n += 1024) {
      const uint4* si = (const uint4*)(lsrc + (size_t)(gbase + n) * DEG_);
      const float4* w4 = (const float4*)(ew + (size_t)(gbase + n) * DEG_);
      uint4 A = si[0], Bq = si[1];
      float4 acc = selfp[n];
      float4 w;
      w = w4[0];
      gacc(acc, w.x, cur[A.x & 0xFFFFu]); gacc(acc, w.y, cur[A.x >> 16]);
      gacc(acc, w.z, cur[A.y & 0xFFFFu]); gacc(acc, w.w, cur[A.y >> 16]);
      w = w4[1];
      gacc(acc, w.x, cur[A.z & 0xFFFFu]); gacc(acc, w.y, cur[A.z >> 16]);
      gacc(acc, w.z, cur[A.w & 0xFFFFu]); gacc(acc, w.w, cur[A.w >> 16]);
      w = w4[2];
      gacc(acc, w.x, cur[Bq.x & 0xFFFFu]); gacc(acc, w.y, cur[Bq.x >> 16]);
      gacc(acc, w.z, cur[Bq.y & 0xFFFFu]); gacc(acc, w.w, cur[Bq.y >> 16]);
      w = w4[3];
      gacc(acc, w.x, cur[Bq.z & 0xFFFFu]); gacc(acc, w.y, cur[Bq.z >> 16]);
      gacc(acc, w.z, cur[Bq.w & 0xFFFFu]); gacc(acc, w.w, cur[Bq.w >> 16]);
      nxt[n] = acc;
    }
    float4* t = cur; cur = nxt; nxt = t;
  }
  __syncthreads();
  float4* op = O4 + (size_t)cg * N2_ + gbase;   // over P3 plane: disjoint per (g,cg)
  float4 s1 = {0.f, 0.f, 0.f, 0.f}, s2 = {0.f, 0.f, 0.f, 0.f};
  for (int n = tid; n < E2_; n += 1024) {
    float4 vv = cur[n];
    op[n] = vv;
    s1.x += vv.x; s1.y += vv.y; s1.z += vv.z; s1.w += vv.w;
    s2.x += vv.x * vv.x; s2.y += vv.y * vv.y; s2.z += vv.z * vv.z; s2.w += vv.w * vv.w;
  }
  for (int o = 32; o; o >>= 1) {
    s1.x += __shfl_down(s1.x, o); s1.y += __shfl_down(s1.y, o);
    s1.z += __shfl_down(s1.z, o); s1.w += __shfl_down(s1.w, o);
    s2.x += __shfl_down(s2.x, o); s2.y += __shfl_down(s2.y, o);
    s2.z += __shfl_down(s2.z, o); s2.w += __shfl_down(s2.w, o);
  }
  if ((tid & 63) == 0) {
    atomicAdd(&sacc[0], s1.x); atomicAdd(&sacc[1], s1.y);
    atomicAdd(&sacc[2], s1.z); atomicAdd(&sacc[3], s1.w);
    atomicAdd(&sacc[4], s2.x); atomicAdd(&sacc[5], s2.y);
    atomicAdd(&sacc[6], s2.z); atomicAdd(&sacc[7], s2.w);
  }
  __syncthreads();
  if (tid < 4) {
    int ch = cg * 4 + tid;
    atomicAdd(&st[ch], (double)sacc[tid]);
    atomicAdd(&st[32 + ch], (double)sacc[4 + tid]);
  }
}

__global__ void k1_params(const double* __restrict__ sum, const double* __restrict__ sq,
    const float* __restrict__ g1, const float* __restrict__ be1,
    float* __restrict__ scale1, float* __restrict__ shiftE1) {
  int c = threadIdx.x;
  if (c >= 32) return;
  double mean = sum[c] / (double)N2_;
  double var = sq[c] / (double)N2_ - mean * mean;
  double sc = (double)g1[c] / sqrt(var + EPS_);
  scale1[c] = (float)sc;
  shiftE1[c] = (float)((double)be1[c] - sc * mean);
}

// =====================================================================
// Layer-2 Horner on 1-channel fields.
// =====================================================================
__global__ __launch_bounds__(256) void k2_proj(const float* __restrict__ X,
    const float* __restrict__ W2, const float* __restrict__ scale1,
    const float* __restrict__ shiftE1,
    float* __restrict__ u0, float* __restrict__ u1,
    float* __restrict__ u2, float* __restrict__ u3) {
  __shared__ float qv[4][32];
  __shared__ float fsc[32], fsh[32];
  int tid = threadIdx.x;
  if (tid < 128) {
    int cp = tid & 31, j = tid >> 5;
    float w0 = W2[cp], w1 = W2[32 + cp], w2 = W2[64 + cp], w3 = W2[96 + cp];
    float q;
    if (j == 0)      q = w0 + w1 + w2 + w3;
    else if (j == 1) q = -w1 - 2.f * w2 - 3.f * w3;
    else if (j == 2) q = 0.5f * w2 + 1.5f * w3;
    else             q = -w3 * (1.f / 6.f);
    qv[j][cp] = q;
  }
  if (tid < 32) { fsc[tid] = scale1[tid]; fsh[tid] = shiftE1[tid]; }
  __syncthreads();
  int node = blockIdx.x * 256 + tid;
  if (node >= N2_) return;
  const float4* xf = (const float4*)X;
  float a0 = 0.f, a1 = 0.f, a2 = 0.f, a3 = 0.f;
#pragma unroll
  for (int t = 0; t < 8; ++t) {
    float4 v = xf[(size_t)t * N2_ + node];
    float f0 = lrelu(fsc[4 * t] * v.x + fsh[4 * t]);
    float f1 = lrelu(fsc[4 * t + 1] * v.y + fsh[4 * t + 1]);
    float f2_ = lrelu(fsc[4 * t + 2] * v.z + fsh[4 * t + 2]);
    float f3 = lrelu(fsc[4 * t + 3] * v.w + fsh[4 * t + 3]);
    a0 += f0 * qv[0][4 * t] + f1 * qv[0][4 * t + 1] + f2_ * qv[0][4 * t + 2] + f3 * qv[0][4 * t + 3];
    a1 += f0 * qv[1][4 * t] + f1 * qv[1][4 * t + 1] + f2_ * qv[1][4 * t + 2] + f3 * qv[1][4 * t + 3];
    a2 += f0 * qv[2][4 * t] + f1 * qv[2][4 * t + 1] + f2_ * qv[2][4 * t + 2] + f3 * qv[2][4 * t + 3];
    a3 += f0 * qv[3][4 * t] + f1 * qv[3][4 * t + 1] + f2_ * qv[3][4 * t + 2] + f3 * qv[3][4 * t + 3];
  }
  u0[node] = a0; u1[node] = a1; u2[node] = a2; u3[node] = a3;
}

// k2_step: 512 threads, grid 512 (2 independent blocks/CU).
__global__ __launch_bounds__(512) void k2_step(const float* __restrict__ z,
    const u16* __restrict__ lsrc, const float* __restrict__ ew,
    const float* __restrict__ u, float* __restrict__ zo,
    int do_stats, double* st2) {
  __shared__ float sz[E2_];
  __shared__ double sred[8][2];
  int g = blockIdx.x >> 3, q = blockIdx.x & 7;
  int gbase = g * E2_;
  for (int j = threadIdx.x; j < E2_; j += 512) sz[j] = z[gbase + j];
  __syncthreads();
  int start = q * SLC2_, end = min(start + SLC2_, E2_);
  double aS = 0.0, aQ = 0.0;
  for (int i = start + (int)threadIdx.x; i < end; i += 512) {
    int node = gbase + i;
    const uint4* si = (const uint4*)(lsrc + (size_t)node * DEG_);
    const float4* w4 = (const float4*)(ew + (size_t)node * DEG_);
    float acc = 0.f;
    GATHER1(acc, sz, si, w4);
    float val = u[node] + acc;
    zo[node] = val;
    if (do_stats) { aS += val; aQ += (double)val * (double)val; }
  }
  if (do_stats) {
    int lane = threadIdx.x & 63, wid = threadIdx.x >> 6;
    for (int o = 32; o; o >>= 1) { aS += __shfl_down(aS, o); aQ += __shfl_down(aQ, o); }
    if (lane == 0) { sred[wid][0] = aS; sred[wid][1] = aQ; }
    __syncthreads();
    if (threadIdx.x == 0) {
      double s = 0.0, qq = 0.0;
#pragma unroll
      for (int w = 0; w < 8; ++w) { s += sred[w][0]; qq += sred[w][1]; }
      atomicAdd(&st2[0], s); atomicAdd(&st2[1], qq);
    }
  }
}

__global__ void k2_params(const double* __restrict__ st2, const float* __restrict__ g2,
    const float* __restrict__ be2, float* __restrict__ p /* [128]=scale2 [129]=shiftE2 */) {
  if (threadIdx.x != 0) return;
  double mean = st2[0] / (double)N2_;
  double var = st2[1] / (double)N2_ - mean * mean;
  double sc = (double)g2[0] / sqrt(var + EPS_);
  p[128] = (float)sc;
  p[129] = (float)((double)be2[0] - sc * mean);
}

// MLP gemm1: 8 batches/block x 32 row-pieces, grid 256.
__global__ __launch_bounds__(256) void k3_gemm1(const float* __restrict__ out2,
    const float* __restrict__ lin1W, const float* __restrict__ p, float* h1pre) {
  __shared__ float f2v[8][144];
  float sc = p[128], sh = p[129];
  int bs = blockIdx.x & 7, rs = blockIdx.x >> 3;
  int b0 = bs * 8;
  int r0 = rs * 141;
  int nr = min(141, E2_ - r0);
  int c = threadIdx.x;
#pragma unroll
  for (int b = 0; b < 8; ++b)
    for (int j = c; j < 144; j += 256)
      f2v[b][j] = (j < nr) ? lrelu(sc * out2[(b0 + b) * E2_ + r0 + j] + sh) : 0.f;
  __syncthreads();
  float acc[8];
#pragma unroll
  for (int b = 0; b < 8; ++b) acc[b] = 0.f;
  int nr4 = nr & ~3;
  int j = 0;
  for (; j < nr4; j += 4) {
    const float* wp = lin1W + (size_t)(r0 + j) * 256 + c;
    float w0 = wp[0], w1 = wp[256], w2 = wp[512], w3 = wp[768];
#pragma unroll
    for (int b = 0; b < 8; ++b) {
      float4 f = *(const float4*)&f2v[b][j];
      acc[b] += f.x * w0 + f.y * w1 + f.z * w2 + f.w * w3;
    }
  }
  for (; j < nr; ++j) {
    float w = lin1W[(size_t)(r0 + j) * 256 + c];
#pragma unroll
    for (int b = 0; b < 8; ++b) acc[b] += f2v[b][j] * w;
  }
#pragma unroll
  for (int b = 0; b < 8; ++b)
    atomicAdd(&h1pre[(b0 + b) * 256 + c], acc[b]);
}

// =====================================================================
// k5_gemm2bn: FUSED BN1+ReLU+gemm2.
// =====================================================================
__global__ __launch_bounds__(256) void k5_gemm2bn(const float* __restrict__ h1pre,
    const float* __restrict__ g, const float* __restrict__ be,
    const float* __restrict__ lin2W, float* __restrict__ h2pre) {
  __shared__ float sh1[64 * 257];
  __shared__ float sred[256];
  int c = blockIdx.x;
  int tid = threadIdx.x;
  for (int i = tid; i < 64 * 256; i += 256) {
    int b = i >> 8, cc = i & 255;
    sh1[b * 257 + cc] = h1pre[i];
  }
  __syncthreads();
  {
    int cc = tid;
    double s = 0.0, qd = 0.0;
    float vs[64];
#pragma unroll
    for (int b = 0; b < 64; ++b) { float v = sh1[b * 257 + cc]; vs[b] = v; s += v; qd += (double)v * v; }
    double mean = s / 64.0, var = qd / 64.0 - mean * mean;
    double scd = (double)g[cc] / sqrt(var + EPS_);
    double shd = (double)be[cc] - scd * mean;
#pragma unroll
    for (int b = 0; b < 64; ++b) {
      float y = (float)(scd * vs[b] + shd);
      sh1[b * 257 + cc] = y > 0.f ? y : 0.f;
    }
  }
  __syncthreads();
  int b = tid & 63, q = tid >> 6;
  float acc = 0.f;
  for (int r = q; r < 256; r += 4) acc += sh1[b * 257 + r] * lin2W[r * 128 + c];
  sred[tid] = acc;
  __syncthreads();
  if (tid < 64)
    h2pre[tid * 128 + c] = sred[tid] + sred[64 + tid] + sred[128 + tid] + sred[192 + tid];
}

// BN2 + ReLU + final linear -> out[64]
__global__ __launch_bounds__(256) void k6_final(const float* __restrict__ h2pre,
    const float* __restrict__ g, const float* __restrict__ be,
    const float* __restrict__ W3, const float* __restrict__ b3, float* __restrict__ outp) {
  __shared__ float sh2[64 * 129];
  __shared__ float sred[256];
  int tid = threadIdx.x;
  if (tid < 128) {
    int c = tid;
    float vs[64];
    double s = 0.0, q = 0.0;
    for (int b = 0; b < 64; ++b) { float v = h2pre[b * 128 + c]; vs[b] = v; s += v; q += (double)v * v; }
    double mean = s / 64.0, var = q / 64.0 - mean * mean;
    double scd = (double)g[c] / sqrt(var + EPS_);
    double shd = (double)be[c] - scd * mean;
    for (int b = 0; b < 64; ++b) {
      float y = (float)(scd * vs[b] + shd);
      sh2[b * 129 + c] = y > 0.f ? y : 0.f;
    }
  }
  __syncthreads();
  int b = tid & 63, q = tid >> 6;
  float acc = 0.f;
  for (int r = q; r < 128; r += 4) acc += sh2[b * 129 + r] * W3[r];
  sred[tid] = acc;
  __syncthreads();
  if (tid < 64)
    outp[tid] = sred[tid] + sred[64 + tid] + sred[128 + tid] + sred[192 + tid] + b3[0];
}

// =====================================================================
extern "C" void kernel_launch(void* const* d_in, const int* in_sizes, int n_in,
                              void* d_out, int out_size, void* d_ws, size_t ws_size,
                              hipStream_t stream) {
  const float* x    = (const float*)d_in[0];
  const int*   ei1  = (const int*)d_in[1];
  const float* ew1  = (const float*)d_in[2];
  const int*   ei2  = (const int*)d_in[3];
  const float* ew2  = (const float*)d_in[4];
  const float* W0   = (const float*)d_in[5];
  const float* g0   = (const float*)d_in[7];
  const float* be0  = (const float*)d_in[8];
  const float* W1   = (const float*)d_in[9];
  const float* g1   = (const float*)d_in[11];
  const float* be1  = (const float*)d_in[12];
  const float* W2   = (const float*)d_in[13];
  const float* g2   = (const float*)d_in[15];
  const float* be2  = (const float*)d_in[16];
  const float* lin1W = (const float*)d_in[17];
  const float* bn1g = (const float*)d_in[19];
  const float* bn1b = (const float*)d_in[20];
  const float* lin2W = (const float*)d_in[21];
  const float* bn2g = (const float*)d_in[23];
  const float* bn2b = (const float*)d_in[24];
  const float* lin3W = (const float*)d_in[25];
  const float* lin3b = (const float*)d_in[26];

  char* ws = (char*)d_ws;
  double* stats  = (double*)ws;                 // [0..13] mom0, [14..45] s1sum, [46..77] s1sq, [78..79] st2
  float*  params = (float*)(ws + 1024);         // [0..31] scale0, [32..63] shiftE0, [64..95] scale1,
                                                // [96..127] shiftE1, [128..129] scale2/shift2, [160..287] scW0
  float*  h1pre  = (float*)(ws + 4096);
  float*  h2pre  = (float*)(ws + 4096 + 131072);
  float*  qb     = (float*)(ws + 196608);       // 4096 floats combined Q weights
  float*  Treg   = (float*)(ws + 262144);
  float* T1_0 = Treg;
  float* T2_0 = Treg + N1_;
  float* T3_0 = Treg + 2 * (size_t)N1_;
  float* u0   = Treg;                           // overlays (T dead after k_poolproj)
  float* u1   = Treg + (size_t)N2_;
  float* u2   = Treg + 2 * (size_t)N2_;
  float* u3   = Treg + 3 * (size_t)N2_;
  float* zA   = Treg + 4 * (size_t)N2_;
  float* out2 = Treg + 5 * (size_t)N2_;         // 6*N2 <= 3*N1  ✓
  float*  big = (float*)(ws + 262144 + 3 * (size_t)N1_ * 4);
  float* bufA = big;                            // hosts lsrc2 (x1 eliminated)
  float* Pbuf = big + 32 * (size_t)N2_;         // 32 planes x N2 float4
  u16* lsrc1 = (u16*)Pbuf;                      // consumed by mv1..3 before Pbuf written
  u16* lsrc2 = (u16*)bufA;

  hipMemsetAsync(stats, 0, 80 * sizeof(double), stream);
  hipMemsetAsync(h1pre, 0, 65536, stream);

  // ---- merged prep: lsrc1 | lsrc2 | qb ----
  k_prep_all<<<3384, 256, 0, stream>>>(ei1, ei2, W1, lsrc1, lsrc2, qb);

  // ---- layer 0 ----
  k0_mv1<<<512, 512, 0, stream>>>(x, lsrc1, ew1, T1_0);
  k0_mv2<<<512, 512, 0, stream>>>(x, lsrc1, ew1, T1_0, T2_0);
  k0_mv3<<<512, 512, 0, stream>>>(x, lsrc1, ew1, T1_0, T2_0, T3_0, stats);
  k0_params<<<1, 32, 0, stream>>>(stats, W0, g0, be0, params, params + 32, params + 160);

  // ---- fused pool + projection to 32 planes (1 row/thread) ----
  k_poolproj<<<(N2_ + 255) / 256, 256, 0, stream>>>(x, T1_0, T2_0, T3_0,
                                                    params + 160, params + 32, qb, (float4*)Pbuf);

  // ---- layer 1 chain ----
  k1_chain<<<512, 1024, 0, stream>>>((const float4*)Pbuf, (float4*)Pbuf, lsrc2, ew2, stats + 14);
  k1_params<<<1, 32, 0, stream>>>(stats + 14, stats + 46, g1, be1, params + 64, params + 96);

  // ---- layer 2 (Horner, 1-channel; out1 = planes 0..7 of Pbuf) ----
  k2_proj<<<(N2_ + 255) / 256, 256, 0, stream>>>(Pbuf, W2, params + 64, params + 96,
                                                 u0, u1, u2, u3);
  k2_step<<<512, 512, 0, stream>>>(u3, lsrc2, ew2, u2, zA, 0, nullptr);       // zA = u2 + L u3
  k2_step<<<512, 512, 0, stream>>>(zA, lsrc2, ew2, u1, u3, 0, nullptr);       // u3slot = u1 + L zA
  k2_step<<<512, 512, 0, stream>>>(u3, lsrc2, ew2, u0, out2, 1, stats + 78);  // out2 + stats
  k2_params<<<1, 64, 0, stream>>>(stats + 78, g2, be2, params);

  // ---- MLP head ----
  k3_gemm1<<<256, 256, 0, stream>>>(out2, lin1W, params, h1pre);
  k5_gemm2bn<<<128, 256, 0, stream>>>(h1pre, bn1g, bn1b, lin2W, h2pre);
  k6_final<<<1, 256, 0, stream>>>(h2pre, bn2g, bn2b, lin3W, lin3b, (float*)d_out);
}